// Round 17
// baseline (296.553 us; speedup 1.0000x reference)
//
#include <hip/hip_runtime.h>

typedef __bf16 bf16;
typedef __bf16 bf16x2 __attribute__((ext_vector_type(2)));
typedef __bf16 bf16x4 __attribute__((ext_vector_type(4)));
typedef __bf16 bf16x8 __attribute__((ext_vector_type(8)));
typedef float f32x4 __attribute__((ext_vector_type(4)));

#define S_LEN 2048
#define HID_DIM 4096
#define NH 32
#define NKV 8
#define HD 128
#define QKV_N 6144   // 4096 Q + 1024 K + 1024 V
#define K_COL 4096
#define V_COL 5120
#define PADV 76

// ------- fused fp32->bf16 conversion (hs, Wq, Wk, Wv) + RoPE tables -------
// Wo conversion is deferred into attn_kernel's tail (rides attn's idle HBM BW).
// Wq/Wk rows PERMUTED so RoPE pairs (d,d+64) land in adjacent qkv columns.
__global__ void cvt_all_kernel(const float* __restrict__ hs, const float* __restrict__ wq,
                               const float* __restrict__ wk, const float* __restrict__ wv,
                               bf16* __restrict__ hsb, bf16* __restrict__ wqkvb,
                               float2* __restrict__ csf) {
  long i = (long)blockIdx.x * blockDim.x + threadIdx.x;
  if (i >= 8388608) {                    // RoPE tables: 2048*64 entries
    int j = (int)(i - 8388608);
    int s = j >> 6, d = j & 63;
    float inv = expf(-0.14391156831212787f * (float)d);   // 10000^(-d/64)
    float ang = (float)s * inv;
    csf[j] = make_float2(cosf(ang), sinf(ang));
    return;
  }
  const float* src; bf16* dst; long off; bool perm = false;
  if (i < 2097152)      { src = hs; dst = hsb;                          off = i; }
  else if (i < 6291456) { src = wq; dst = wqkvb;                        off = i - 2097152; perm = true; }
  else if (i < 7340032) { src = wk; dst = wqkvb + (long)4096 * 4096;    off = i - 6291456; perm = true; }
  else                  { src = wv; dst = wqkvb + (long)5120 * 4096;    off = i - 7340032; }
  float4 v = reinterpret_cast<const float4*>(src)[off];
  bf16x4 o;
  o[0] = (bf16)v.x; o[1] = (bf16)v.y; o[2] = (bf16)v.z; o[3] = (bf16)v.w;
  long doff = off;
  if (perm) {
    long r = off >> 10, c4 = off & 1023;
    long d = r & 127;
    long pd = ((d & 63) << 1) | (d >> 6);
    doff = (((r & ~127L) | pd) << 10) | c4;
  }
  reinterpret_cast<bf16x4*>(dst)[doff] = o;
}

// ---- 4-phase GEMM: BM=256, BN=NB*64, BK=64 (R8 schedule) + optional fused RoPE ----
#define STG8(buf, mat, kt, unit) {                                                       \
    const bf16* sp_ = (mat) ? Bp : Ap;                                                   \
    int row0_ = ((mat) ? n0 : m0) + (unit) * 64;                                         \
    int lb_ = (buf) * LBUF + (mat) * 16384 + (unit) * 4096;                              \
    int r_ = t >> 3, jl_ = t & 7, jg_ = jl_ ^ (r_ & 7);                                  \
    const bf16* src_ = sp_ + (long)(row0_ + r_) * K + (kt) * 64 + jg_ * 8;               \
    __builtin_amdgcn_global_load_lds((const __attribute__((address_space(1))) void*)src_,\
        (__attribute__((address_space(3))) void*)(L + lb_ + t * 8), 16, 0, 0); }

#define DSA2(buf, mh) {                                                                  \
    _Pragma("unroll") for (int ks_ = 0; ks_ < 2; ++ks_)                                  \
      _Pragma("unroll") for (int mf_ = 0; mf_ < 4; ++mf_) {                              \
        int R_ = wr * 128 + (mh) * 64 + mf_ * 16 + lm;                                   \
        aF[ks_][mf_] = *reinterpret_cast<const bf16x8*>(                                 \
            L + (buf) * LBUF + R_ * 64 + (((ks_ * 4 + lg) ^ (R_ & 7)) << 3));            \
      } }

#define DSBALL(buf) {                                                                    \
    _Pragma("unroll") for (int ks_ = 0; ks_ < 2; ++ks_)                                  \
      _Pragma("unroll") for (int nf_ = 0; nf_ < NB; ++nf_) {                             \
        int R_ = wc * (NB * 16) + nf_ * 16 + lm;                                         \
        bF[ks_][nf_] = *reinterpret_cast<const bf16x8*>(                                 \
            L + (buf) * LBUF + 16384 + R_ * 64 + (((ks_ * 4 + lg) ^ (R_ & 7)) << 3));    \
      } }

#define MM2(mh) {                                                                        \
    __builtin_amdgcn_s_setprio(1);                                                       \
    _Pragma("unroll") for (int mf_ = 0; mf_ < 4; ++mf_)                                  \
      _Pragma("unroll") for (int nf_ = 0; nf_ < NB; ++nf_)                               \
        _Pragma("unroll") for (int ks_ = 0; ks_ < 2; ++ks_)                              \
          acc[(mh) * 4 + mf_][nf_] = __builtin_amdgcn_mfma_f32_16x16x32_bf16(            \
              aF[ks_][mf_], bF[ks_][nf_], acc[(mh) * 4 + mf_][nf_], 0, 0, 0);            \
    __builtin_amdgcn_s_setprio(0); }

#define BAR() __builtin_amdgcn_s_barrier()
#define WVM(n) asm volatile("s_waitcnt vmcnt(%0)" :: "i"(n) : "memory")

template<int NB, bool ROPE, typename OutT>
__global__ __launch_bounds__(512, 1) void gemm4p_kernel(
    const bf16* __restrict__ Ap, const bf16* __restrict__ Bp, OutT* __restrict__ C,
    int M, int N, int K, const float2* __restrict__ csf) {
  constexpr int LBUF = 16384 + NB * 4096;
  __shared__ __align__(16) bf16 L[2 * LBUF];

  int nwg = gridDim.x * gridDim.y;
  int bid = blockIdx.y * gridDim.x + blockIdx.x;
  int cpx = nwg >> 3;
  int swz = (bid & 7) * cpx + (bid >> 3);
  int bxs = swz % gridDim.x, bys = swz / gridDim.x;
  const int n0 = bxs * (NB * 64), m0 = bys * 256;

  const int t = threadIdx.x;
  const int lane = t & 63, w = t >> 6;
  const int wr = w >> 2, wc = w & 3;
  const int lg = lane >> 4, lm = lane & 15;
  const int NT = K >> 6;

  f32x4 acc[8][NB] = {};
  bf16x8 aF[2][4], bF[2][NB];

  STG8(0, 0, 0, 0); STG8(0, 0, 0, 1); STG8(0, 0, 0, 2); STG8(0, 0, 0, 3);
  STG8(0, 1, 0, 0); if (NB > 1) STG8(0, 1, 0, 1); if (NB > 2) STG8(0, 1, 0, 2);
  STG8(1, 1, 1, 0); if (NB > 1) STG8(1, 1, 1, 1); if (NB > 2) STG8(1, 1, 1, 2);
  WVM(NB);
  BAR();

  for (int I = 0; I < (NT >> 1); ++I) {
    const int tt = 2 * I;
    const bool pf = (I < (NT >> 1) - 1);
    DSA2(0, 0); DSBALL(0);
    STG8(1, 0, tt + 1, 0); STG8(1, 0, tt + 1, 1);
    STG8(1, 0, tt + 1, 2); STG8(1, 0, tt + 1, 3);
    BAR(); MM2(0); BAR();
    DSA2(0, 1);
    if (pf) { STG8(0, 1, tt + 2, 0); if (NB > 1) STG8(0, 1, tt + 2, 1);
              if (NB > 2) STG8(0, 1, tt + 2, 2); }
    BAR(); MM2(1);
    if (pf) WVM(NB); else WVM(0);
    BAR();
    DSA2(1, 0); DSBALL(1);
    if (pf) { STG8(0, 0, tt + 2, 0); STG8(0, 0, tt + 2, 1);
              STG8(0, 0, tt + 2, 2); STG8(0, 0, tt + 2, 3); }
    BAR(); MM2(0); BAR();
    DSA2(1, 1);
    if (pf) { STG8(1, 1, tt + 3, 0); if (NB > 1) STG8(1, 1, tt + 3, 1);
              if (NB > 2) STG8(1, 1, tt + 3, 2); }
    BAR(); MM2(1);
    if (pf) WVM(NB); else WVM(0);
    BAR();
  }

  // ---- epilogue (optionally fused RoPE for Q/K columns) ----
#pragma unroll
  for (int am = 0; am < 8; ++am) {
    int row = m0 + wr * 128 + am * 16 + lg * 4;
#pragma unroll
    for (int nf = 0; nf < NB; ++nf) {
      int col = n0 + wc * (NB * 16) + nf * 16 + lm;
      if (ROPE && col < V_COL) {
        int j = (col & 127) >> 1;
        bool odd = col & 1;
#pragma unroll
        for (int rr = 0; rr < 4; ++rr) {
          float x = acc[am][nf][rr];
          float xp = __shfl_xor(x, 1);
          int s = row + rr;
          float2 cs = csf[(s << 6) | j];
          float y = odd ? (x * cs.x + xp * cs.y) : (x * cs.x - xp * cs.y);
          C[(long)s * N + col] = (bf16)y;
        }
      } else {
#pragma unroll
        for (int rr = 0; rr < 4; ++rr) {
          float v = acc[am][nf][rr];
          if constexpr (sizeof(OutT) == 4) C[(long)(row + rr) * N + col] = v;
          else                             C[(long)(row + rr) * N + col] = (bf16)v;
        }
      }
    }
  }
}

// ---------------- GQA causal flash attention, v9 + BALANCED Wo-conversion tail ----------------
// Tail work proportional to (16 - qt). FIXED prefix math: 8 groups per half,
// total weight = 32*(36 + 100) = 4352 units; U = ceil(4194304/4352) = 964.
#define AK_BAR() { asm volatile("s_waitcnt vmcnt(2)" ::: "memory");                      \
                   __builtin_amdgcn_sched_barrier(0);                                    \
                   asm volatile("s_waitcnt lgkmcnt(0)" ::: "memory");                    \
                   __builtin_amdgcn_s_barrier(); }

#define AK_WRITEV(r0, r1, vtb) {                                                         \
    _Pragma("unroll") for (int e = 0; e < 8; ++e) {                                      \
      bf16x2 pk; pk[0] = r0[e]; pk[1] = r1[e];                                           \
      *reinterpret_cast<bf16x2*>(Vt[vtb] + (dchunk * 8 + e) * PADV + slot) = pk;         \
    } }

#define AK_ISSUEV(base, r0, r1) {                                                        \
    long rv_ = (long)(base) + kva; if (rv_ > 2046) rv_ = 2046;                           \
    const bf16* vs_ = vbase + rv_ * QKV_N + dchunk * 8;                                  \
    r0 = *reinterpret_cast<const bf16x8*>(vs_);                                          \
    r1 = *reinterpret_cast<const bf16x8*>(vs_ + QKV_N); }

#define AK_ISSUEK(base, buf) {                                                           \
    _Pragma("unroll") for (int i_ = 0; i_ < 2; ++i_) {                                   \
      int c_ = i_ * 512 + t;                                                             \
      int r_ = c_ >> 4, jl_ = c_ & 15, jg_ = jl_ ^ (r_ & 15);                            \
      long rk_ = (long)(base) + r_; if (rk_ > 2047) rk_ = 2047;                          \
      const bf16* src_ = kbase + rk_ * QKV_N + jg_ * 8;                                  \
      __builtin_amdgcn_global_load_lds((const __attribute__((address_space(1))) void*)src_,\
          (__attribute__((address_space(3))) void*)(Ks[buf] + c_ * 8), 16, 0, 0);        \
    } }

#define AK_STEP(stv, bufb) {                                                             \
    const int st_ = (stv);                                                               \
    const int kv0_ = st_ * 64;                                                           \
    if (kv0_ <= q0 + w * 16 + 15) {                                                      \
      f32x4 s[4];                                                                        \
      _Pragma("unroll") for (int cb = 0; cb < 4; ++cb) s[cb] = f32x4{0.f,0.f,0.f,0.f};   \
      __builtin_amdgcn_s_setprio(1);                                                     \
      _Pragma("unroll") for (int ks = 0; ks < 4; ++ks)                                   \
        _Pragma("unroll") for (int cb = 0; cb < 4; ++cb) {                               \
          bf16x8 kf = *reinterpret_cast<const bf16x8*>(                                  \
              Ks[bufb] + (cb * 16 + lm) * 128 + (((ks * 4 + lg) ^ lm) << 3));            \
          s[cb] = __builtin_amdgcn_mfma_f32_16x16x32_bf16(kf, qf[ks], s[cb], 0, 0, 0);   \
        }                                                                                \
      __builtin_amdgcn_s_setprio(0);                                                     \
      const float SC = 0.12751742f;                                                      \
      float sl[4][4];                                                                    \
      _Pragma("unroll") for (int cb = 0; cb < 4; ++cb)                                   \
        _Pragma("unroll") for (int r = 0; r < 4; ++r) {                                  \
          float v = s[cb][r] * SC;                                                       \
          if (st_ >= nst - 2 && (kv0_ + cb * 16 + lg * 4 + r) > qg) v = -1e30f;          \
          sl[cb][r] = v;                                                                 \
        }                                                                                \
      float tm = sl[0][0];                                                               \
      _Pragma("unroll") for (int cb = 0; cb < 4; ++cb)                                   \
        _Pragma("unroll") for (int r = 0; r < 4; ++r) tm = fmaxf(tm, sl[cb][r]);         \
      tm = fmaxf(tm, __shfl_xor(tm, 16));                                                \
      tm = fmaxf(tm, __shfl_xor(tm, 32));                                                \
      if (__any(tm > mrow + 8.f)) {                                                      \
        float mnew = fmaxf(mrow, tm);                                                    \
        float alpha = exp2f(mrow - mnew);                                                \
        mrow = mnew; lrow *= alpha;                                                      \
        float ar[4];                                                                     \
        _Pragma("unroll") for (int r = 0; r < 4; ++r)                                    \
          ar[r] = __shfl(alpha, (lane & 48) | (lg * 4 + r));                             \
        _Pragma("unroll") for (int i = 0; i < 8; ++i)                                    \
          _Pragma("unroll") for (int r = 0; r < 4; ++r) o[i][r] *= ar[r];                \
      }                                                                                  \
      float p[4][4]; float psum = 0.f;                                                   \
      _Pragma("unroll") for (int cb = 0; cb < 4; ++cb)                                   \
        _Pragma("unroll") for (int r = 0; r < 4; ++r) {                                  \
          p[cb][r] = exp2f(sl[cb][r] - mrow); psum += p[cb][r];                          \
        }                                                                                \
      psum += __shfl_xor(psum, 16);                                                      \
      psum += __shfl_xor(psum, 32);                                                      \
      lrow += psum;                                                                      \
      bf16x8 pa0, pa1;                                                                   \
      _Pragma("unroll") for (int r = 0; r < 4; ++r) {                                    \
        pa0[r] = (bf16)p[0][r]; pa0[4 + r] = (bf16)p[1][r];                              \
        pa1[r] = (bf16)p[2][r]; pa1[4 + r] = (bf16)p[3][r];                              \
      }                                                                                  \
      __builtin_amdgcn_s_setprio(1);                                                     \
      _Pragma("unroll") for (int db = 0; db < 8; ++db) {                                 \
        bf16x8 vf0 = *reinterpret_cast<const bf16x8*>(Vt[bufb] + (db*16+lm)*PADV + lg*8);\
        bf16x8 vf1 = *reinterpret_cast<const bf16x8*>(Vt[bufb] + (db*16+lm)*PADV + 32 + lg*8);\
        o[db] = __builtin_amdgcn_mfma_f32_16x16x32_bf16(pa0, vf0, o[db], 0, 0, 0);       \
        o[db] = __builtin_amdgcn_mfma_f32_16x16x32_bf16(pa1, vf1, o[db], 0, 0, 0);       \
      }                                                                                  \
      __builtin_amdgcn_s_setprio(0);                                                     \
    } }

__global__ __launch_bounds__(512, 4) void attn_kernel(const bf16* __restrict__ qkv,
                                                      bf16* __restrict__ out,
                                                      const float* __restrict__ wo,
                                                      bf16* __restrict__ wob) {
  __shared__ __align__(16) bf16 Ks[2][64 * 128];
  __shared__ __align__(16) bf16 Vt[2][128 * PADV];

  const int bx = blockIdx.x;
  // balanced CU pairing: block c (c<256) gets qt=15-(c>>5), block c+256 gets qt=(c>>5)
  const int g = (bx & 255) >> 5;        // 8 groups per half (g in 0..7)
  const int qt = (bx < 256) ? (15 - g) : g;
  const int h = bx & 31;                // head -> fixed XCD: KV L2 locality
  const int kvh = h >> 2;               // GROUPS = 4
  const int q0 = qt * 128;
  const int t = threadIdx.x, lane = t & 63, w = t >> 6;   // 8 waves
  const int lg = lane >> 4, lm = lane & 15;
  const int dchunk = t >> 5, kv2 = t & 31;
  const int kva = kv2 * 2;
  const int k5 = kva & 31;
  const int slot = ((kva >> 5) << 5) | (((k5 >> 2) & 3) << 3) | ((k5 >> 4) << 2) | (k5 & 3);
  const bf16* kbase = qkv + K_COL + kvh * HD;
  const bf16* vbase = qkv + V_COL + kvh * HD;

  const long qrow = q0 + w * 16 + lm;
  const int qg = q0 + w * 16 + lm;
  bf16x8 qf[4];
#pragma unroll
  for (int ks = 0; ks < 4; ++ks)
    qf[ks] = *reinterpret_cast<const bf16x8*>(qkv + qrow * QKV_N + h * HD + ks * 32 + lg * 8);

  f32x4 o[8];
#pragma unroll
  for (int i = 0; i < 8; ++i) o[i] = f32x4{0.f, 0.f, 0.f, 0.f};
  float mrow = -1e30f, lrow = 0.f;

  const int nst = 2 * qt + 2;
  bf16x8 va0, va1, vb0, vb1;

  // ---- prologue ----
  AK_ISSUEK(0, 0);
  AK_ISSUEV(0, va0, va1);
  AK_WRITEV(va0, va1, 0);
  AK_ISSUEV(64, vb0, vb1);
  asm volatile("s_waitcnt lgkmcnt(0)" ::: "memory");
  __builtin_amdgcn_s_barrier();

  for (int I = 0; I < (nst >> 1); ++I) {
    const int s0 = 2 * I;
    AK_ISSUEK((s0 + 1) * 64, 1);
    AK_ISSUEV((s0 + 2) * 64, va0, va1);
    AK_WRITEV(vb0, vb1, 1);
    AK_STEP(s0, 0);
    AK_BAR();
    AK_ISSUEK((s0 + 2) * 64, 0);
    AK_ISSUEV((s0 + 3) * 64, vb0, vb1);
    AK_WRITEV(va0, va1, 0);
    AK_STEP(s0 + 1, 1);
    AK_BAR();
  }

  // ---- epilogue: normalize + store ----
  float invr[4];
#pragma unroll
  for (int r = 0; r < 4; ++r)
    invr[r] = 1.0f / __shfl(lrow, (lane & 48) | (lg * 4 + r));
#pragma unroll
  for (int r = 0; r < 4; ++r) {
    long row = q0 + w * 16 + lg * 4 + r;
#pragma unroll
    for (int db = 0; db < 8; ++db)
      out[row * HID_DIM + h * HD + db * 16 + lm] = (bf16)(o[db][r] * invr[r]);
  }

  // ---- tail: Wo fp32->bf16, work proportional to (16 - qt) [FIXED prefix math] ----
  // weights: first half wgt=1+g, second half wgt=16-g (g in 0..7); total 4352 units.
  {
    const int wgt = 16 - qt;
    long pfx;
    if (bx < 256) {
      // preceding groups j=0..g-1 weigh (1+j), 32 blocks each
      pfx = 32L * ((long)g * (g + 1) / 2) + (long)(bx & 31) * wgt;
    } else {
      // first half total = 32 * 36 = 1152; preceding 2nd-half groups weigh (16-j)
      long t2 = 16L * g - (long)g * (g - 1) / 2;     // sum_{j<g} (16-j)
      pfx = 1152L + 32L * t2 + (long)(bx & 31) * wgt;
    }
    const long U = 964;                                // ceil(4194304 / 4352)
    long start = pfx * U;
    long cnt = (long)wgt * U;
    if (start > 4194304) start = 4194304;
    if (start + cnt > 4194304) cnt = 4194304 - start;
    const float4* wsrc = reinterpret_cast<const float4*>(wo);
    bf16x4* wdst = reinterpret_cast<bf16x4*>(wob);
    for (long idx = start + t; idx < start + cnt; idx += 512) {
      float4 v = wsrc[idx];
      bf16x4 o4;
      o4[0] = (bf16)v.x; o4[1] = (bf16)v.y; o4[2] = (bf16)v.z; o4[3] = (bf16)v.w;
      wdst[idx] = o4;
    }
  }
}

extern "C" void kernel_launch(void* const* d_in, const int* in_sizes, int n_in,
                              void* d_out, int out_size, void* d_ws, size_t ws_size,
                              hipStream_t stream) {
  const float* hs = (const float*)d_in[0];
  const float* Wq = (const float*)d_in[1];
  const float* Wk = (const float*)d_in[2];
  const float* Wv = (const float*)d_in[3];
  const float* Wo = (const float*)d_in[4];
  float* out = (float*)d_out;
  char* ws = (char*)d_ws;

  bf16*   hsb   = (bf16*)(ws);                    // 2048x4096 bf16
  bf16*   wqkvb = (bf16*)(ws + 16777216);         // 6144x4096 bf16
  bf16*   wob   = (bf16*)(ws + 67108864);         // 4096x4096 bf16
  bf16*   qkv   = (bf16*)(ws + 100663296);        // 2048x6144 bf16
  bf16*   attn  = (bf16*)(ws + 125829120);        // 2048x4096 bf16
  float2* csf   = (float2*)(ws + 142606336);      // 2048x64 float2 (cos,sin)

  cvt_all_kernel<<<33280, 256, 0, stream>>>(hs, Wq, Wk, Wv, hsb, wqkvb, csf);
  gemm4p_kernel<3, true, bf16><<<dim3(32, 8), 512, 0, stream>>>(hsb, wqkvb, qkv, 2048, 6144, 4096, csf);
  attn_kernel<<<512, 512, 0, stream>>>(qkv, attn, Wo, wob);
  gemm4p_kernel<2, false, float><<<dim3(32, 8), 512, 0, stream>>>(attn, wob, out, 2048, 4096, 4096, nullptr);
}